// Round 18
// baseline (907.342 us; speedup 1.0000x reference)
//
#include <hip/hip_runtime.h>

typedef unsigned short ushort_t;
typedef __attribute__((ext_vector_type(4))) float f32x4;
typedef __attribute__((ext_vector_type(8))) short short8;

__device__ __forceinline__ ushort_t f2bf(float f) {
  union { float f; unsigned u; } v; v.f = f;
  unsigned r = v.u + 0x7fffu + ((v.u >> 16) & 1u);
  return (ushort_t)(r >> 16);
}
__device__ __forceinline__ unsigned pack2(float lo, float hi) {
  return (unsigned)f2bf(lo) | ((unsigned)f2bf(hi) << 16);
}

// ---------------- kernel 0: fused weight-cvt + x transpose ----------------------
__global__ __launch_bounds__(256) void prep_k(const float* __restrict__ x,
                                              const float* __restrict__ wq,
                                              const float* __restrict__ wk,
                                              const float* __restrict__ wv,
                                              const float* __restrict__ wo,
                                              ushort_t* __restrict__ wB,
                                              ushort_t* __restrict__ xT) {
  __shared__ ushort_t tile[128 * 80];
  int bid = blockIdx.x;
  int tid = threadIdx.x;
  if (bid < 1024) {
    int idx = (bid * 256 + tid) * 4;
    int m = idx >> 18;
    int off = idx & 0x3ffff;
    const float* s = (m == 0) ? wq : (m == 1) ? wk : (m == 2) ? wv : wo;
    float4 v = *(const float4*)(s + off);
    ushort4 o;
    o.x = f2bf(v.x); o.y = f2bf(v.y); o.z = f2bf(v.z); o.w = f2bf(v.w);
    *(ushort4*)(wB + idx) = o;
    return;
  }
  int xb_id = bid - 1024;
  int win = xb_id >> 2, kc = xb_id & 3;
  int b = win / 576, rem = win % 576, wh = rem / 24, ww = rem % 24;
  {
    int c_l = tid >> 1, half = tid & 1;
    const float* xb = x + ((((size_t)b * 512 + kc * 128 + c_l) * 192 + wh * 8) * 192 + ww * 8);
#pragma unroll
    for (int ii = 0; ii < 4; ++ii) {
      int i = half * 4 + ii;
      float4 v0 = *(const float4*)(xb + i * 192);
      float4 v1 = *(const float4*)(xb + i * 192 + 4);
      uint4 u;
      u.x = (unsigned)f2bf(v0.x) | ((unsigned)f2bf(v0.y) << 16);
      u.y = (unsigned)f2bf(v0.z) | ((unsigned)f2bf(v0.w) << 16);
      u.z = (unsigned)f2bf(v1.x) | ((unsigned)f2bf(v1.y) << 16);
      u.w = (unsigned)f2bf(v1.z) | ((unsigned)f2bf(v1.w) << 16);
      *(uint4*)&tile[c_l * 80 + i * 8] = u;
    }
  }
  __syncthreads();
  {
    int tok = tid >> 2, q = tid & 3;
    unsigned w[16];
#pragma unroll
    for (int k = 0; k < 16; ++k) {
      unsigned lo = tile[(q * 32 + 2 * k) * 80 + tok];
      unsigned hi = tile[(q * 32 + 2 * k + 1) * 80 + tok];
      w[k] = lo | (hi << 16);
    }
    ushort_t* d = xT + ((size_t)(win * 64 + tok) * 512 + kc * 128 + q * 32);
#pragma unroll
    for (int s2 = 0; s2 < 4; ++s2) {
      uint4 u; u.x = w[s2 * 4 + 0]; u.y = w[s2 * 4 + 1]; u.z = w[s2 * 4 + 2]; u.w = w[s2 * 4 + 3];
      *(uint4*)(d + s2 * 8) = u;
    }
  }
}

// ---------------- kernel 1: fully fused QKV + attention + out-projection --------
// Grid 2304 (XCD-swizzled), block 512 (8 waves), 152 KB LDS (1 block/CU).
// Per head-pair hcc: QKV (barrier-free 192-MFMA run) -> attention -> O into LDS
// obuf half. After hcc=1 and hcc=3: proj K-half pass accumulating into pacc
// (64 AGPRs, persistent). Epilogue scatters fp32 out directly. O never touches
// global memory; proj kernel and its staging eliminated.
__global__ __launch_bounds__(512, 1) void fused_k(const ushort_t* __restrict__ xT,
                                                  const ushort_t* __restrict__ wB,
                                                  const float* __restrict__ beta,
                                                  const float* __restrict__ bo,
                                                  float* __restrict__ out) {
  __shared__ ushort_t xws[64 * 520];     // 66560 B
  __shared__ ushort_t qs[2][64 * 72];    // 18432 B (reused as P)
  __shared__ ushort_t ks[2][64 * 72];    // 18432 B
  __shared__ ushort_t vs[2][64 * 72];    // 18432 B
  __shared__ ushort_t obuf[64 * 264];    // 33792 B  [tok][256ch half + pad 8]
  int bid = blockIdx.x;
  int win = (bid & 7) * 288 + (bid >> 3);   // neighbors share XCD (out locality)
  int b = win / 576, rem = win % 576, wh = rem / 24, ww = rem % 24;
  int t0 = win * 64;
  int tid = threadIdx.x, lane = tid & 63, wid = tid >> 6;
  int l15 = lane & 15, l4 = lane >> 4;

  // ---- stage full window xT into LDS once ----
  {
    int token = tid >> 3, cb = (tid & 7) * 64;
    const uint4* src = (const uint4*)(xT + (size_t)(t0 + token) * 512 + cb);
    uint4* dst = (uint4*)&xws[token * 520 + cb];
#pragma unroll
    for (int s2 = 0; s2 < 8; ++s2) dst[s2] = src[s2];
  }
  __syncthreads();

  const f32x4 z = {0.f, 0.f, 0.f, 0.f};
  const ushort_t* woB = wB + 3 * 262144;

  // persistent proj accumulator: wave wid -> out rows [wid*64, +64)
  f32x4 pacc[4][4];
#pragma unroll
  for (int i = 0; i < 4; ++i)
#pragma unroll
    for (int j = 0; j < 4; ++j) pacc[i][j] = z;

  for (int hcc = 0; hcc < 4; ++hcc) {
    // ---- QKV for head pair hcc: barrier-free run of 192 MFMAs ----
    f32x4 aq[4], ak[4], av[4];
#pragma unroll
    for (int i = 0; i < 4; ++i) { aq[i] = z; ak[i] = z; av[i] = z; }
    int ocol = hcc * 128 + wid * 16 + l15;
    const ushort_t* wqr = wB + (size_t)ocol * 512 + l4 * 8;
    const ushort_t* wkr = wqr + 262144;
    const ushort_t* wvr = wqr + 524288;
#pragma unroll
    for (int kk = 0; kk < 16; ++kk) {
      short8 bq = *(const short8*)(wqr + kk * 32);
      short8 bk = *(const short8*)(wkr + kk * 32);
      short8 bv = *(const short8*)(wvr + kk * 32);
#pragma unroll
      for (int nt = 0; nt < 4; ++nt) {
        short8 a = *(const short8*)&xws[(nt * 16 + l15) * 520 + kk * 32 + l4 * 8];
        aq[nt] = __builtin_amdgcn_mfma_f32_16x16x32_bf16(a, bq, aq[nt], 0, 0, 0);
        ak[nt] = __builtin_amdgcn_mfma_f32_16x16x32_bf16(a, bk, ak[nt], 0, 0, 0);
        av[nt] = __builtin_amdgcn_mfma_f32_16x16x32_bf16(a, bv, av[nt], 0, 0, 0);
      }
    }
    // write q,k (token-major) and v (d-major); prev round's readers done
    // (trailing barrier of prev round / staging barrier for hcc=0)
    int hw = wid >> 2;
    int dd = (wid * 16 + l15) & 63;
#pragma unroll
    for (int nt = 0; nt < 4; ++nt) {
#pragma unroll
      for (int r = 0; r < 4; ++r) {
        int n = nt * 16 + l4 * 4 + r;
        qs[hw][n * 72 + dd] = f2bf(aq[nt][r]);
        ks[hw][n * 72 + dd] = f2bf(ak[nt][r]);
      }
      uint2 u;
      u.x = pack2(av[nt][0], av[nt][1]);
      u.y = pack2(av[nt][2], av[nt][3]);
      *(uint2*)&vs[hw][dd * 72 + nt * 16 + l4 * 4] = u;
    }
    __syncthreads();

    // ---- attention: wave -> head hh = wid>>2, rows rowg*16.. ----
    int hh = wid >> 2, rowg = wid & 3;
    int h = hcc * 2 + hh;
    f32x4 sA[4];
#pragma unroll
    for (int i = 0; i < 4; ++i) sA[i] = z;
#pragma unroll
    for (int kk = 0; kk < 2; ++kk) {
      short8 aF = *(const short8*)&qs[hh][(rowg * 16 + l15) * 72 + kk * 32 + l4 * 8];
#pragma unroll
      for (int mt = 0; mt < 4; ++mt) {
        short8 bF = *(const short8*)&ks[hh][(mt * 16 + l15) * 72 + kk * 32 + l4 * 8];
        sA[mt] = __builtin_amdgcn_mfma_f32_16x16x32_bf16(aF, bF, sA[mt], 0, 0, 0);
      }
    }
    const float* betah = beta + h * 4096;
    float p[4][4];
    float rmax[4] = {-1e30f, -1e30f, -1e30f, -1e30f};
#pragma unroll
    for (int mt = 0; mt < 4; ++mt)
#pragma unroll
      for (int r = 0; r < 4; ++r) {
        int n = rowg * 16 + l4 * 4 + r;
        float val = sA[mt][r] * 0.125f + betah[n * 64 + mt * 16 + l15];
        p[mt][r] = val;
        rmax[r] = fmaxf(rmax[r], val);
      }
#pragma unroll
    for (int m = 1; m <= 8; m <<= 1)
#pragma unroll
      for (int r = 0; r < 4; ++r) rmax[r] = fmaxf(rmax[r], __shfl_xor(rmax[r], m, 64));
    float rsum[4] = {0.f, 0.f, 0.f, 0.f};
#pragma unroll
    for (int mt = 0; mt < 4; ++mt)
#pragma unroll
      for (int r = 0; r < 4; ++r) {
        p[mt][r] = __expf(p[mt][r] - rmax[r]);
        rsum[r] += p[mt][r];
      }
#pragma unroll
    for (int m = 1; m <= 8; m <<= 1)
#pragma unroll
      for (int r = 0; r < 4; ++r) rsum[r] += __shfl_xor(rsum[r], m, 64);
    float rinv[4];
#pragma unroll
    for (int r = 0; r < 4; ++r) rinv[r] = 1.f / rsum[r];
    // P overwrites this wave's own 16 rows of qs[hh]; same-wave DS ordering
#pragma unroll
    for (int mt = 0; mt < 4; ++mt)
#pragma unroll
      for (int r = 0; r < 4; ++r)
        qs[hh][(rowg * 16 + l4 * 4 + r) * 72 + mt * 16 + l15] = f2bf(p[mt][r] * rinv[r]);

    f32x4 oA[4];
#pragma unroll
    for (int i = 0; i < 4; ++i) oA[i] = z;
#pragma unroll
    for (int kk = 0; kk < 2; ++kk) {
      short8 aF = *(const short8*)&qs[hh][(rowg * 16 + l15) * 72 + kk * 32 + l4 * 8];
#pragma unroll
      for (int dt = 0; dt < 4; ++dt) {
        short8 bF = *(const short8*)&vs[hh][(dt * 16 + l15) * 72 + kk * 32 + l4 * 8];
        oA[dt] = __builtin_amdgcn_mfma_f32_16x16x32_bf16(aF, bF, oA[dt], 0, 0, 0);
      }
    }
    // ---- O to LDS obuf half: local col = (hcc&1)*128 + hh*64 + dt*16 + l15 ----
#pragma unroll
    for (int dt = 0; dt < 4; ++dt) {
      int col = (hcc & 1) * 128 + hh * 64 + dt * 16 + l15;
#pragma unroll
      for (int r = 0; r < 4; ++r) {
        int n = rowg * 16 + l4 * 4 + r;
        obuf[n * 264 + col] = f2bf(oA[dt][r]);
      }
    }
    __syncthreads();  // obuf half visible / qs/ks/vs reads done before next round

    // ---- proj K-half pass after hcc=1 (p=0) and hcc=3 (p=1) ----
    if (hcc & 1) {
      int pp = hcc >> 1;
#pragma unroll
      for (int kcc = 0; kcc < 2; ++kcc) {
#pragma unroll
        for (int kk = 0; kk < 4; ++kk) {
          int cg = kcc * 128 + kk * 32 + l4 * 8;
          short8 bF[4];
#pragma unroll
          for (int nt = 0; nt < 4; ++nt)
            bF[nt] = *(const short8*)&obuf[(nt * 16 + l15) * 264 + cg];
#pragma unroll
          for (int mt = 0; mt < 4; ++mt) {
            int orow = wid * 64 + mt * 16 + l15;
            short8 aF = *(const short8*)(woB + (size_t)orow * 512 + pp * 256 + cg);
#pragma unroll
            for (int nt = 0; nt < 4; ++nt)
              pacc[mt][nt] = __builtin_amdgcn_mfma_f32_16x16x32_bf16(aF, bF[nt], pacc[mt][nt], 0, 0, 0);
          }
        }
      }
      // no barrier needed here: next round's obuf writes are behind its own
      // two barriers, so all waves' proj reads complete first.
    }
  }

  // ---- epilogue: scatter out = pacc + bo ----
#pragma unroll
  for (int mt = 0; mt < 4; ++mt) {
#pragma unroll
    for (int r = 0; r < 4; ++r) {
      int o = wid * 64 + mt * 16 + l4 * 4 + r;
      float bias = bo[o];
#pragma unroll
      for (int nt = 0; nt < 4; ++nt) {
        int tok = nt * 16 + l15;
        int i = tok >> 3, j = tok & 7;
        out[(((size_t)b * 512 + o) * 192 + wh * 8 + i) * 192 + ww * 8 + j] = pacc[mt][nt][r] + bias;
      }
    }
  }
}

extern "C" void kernel_launch(void* const* d_in, const int* in_sizes, int n_in,
                              void* d_out, int out_size, void* d_ws, size_t ws_size,
                              hipStream_t stream) {
  const float* x    = (const float*)d_in[0];
  const float* wq   = (const float*)d_in[1];
  const float* wk   = (const float*)d_in[2];
  const float* wv   = (const float*)d_in[3];
  const float* wo   = (const float*)d_in[4];
  const float* bo   = (const float*)d_in[5];
  const float* beta = (const float*)d_in[6];

  // d_ws layout: wB 2 MiB | xT 151 MB   (O buffer eliminated)
  ushort_t* wB = (ushort_t*)d_ws;
  ushort_t* xT = (ushort_t*)((char*)d_ws + (size_t)2097152);

  prep_k<<<10240, 256, 0, stream>>>(x, wq, wk, wv, wo, wB, xT);
  fused_k<<<2304, 512, 0, stream>>>(xT, wB, beta, bo, (float*)d_out);
}

// Round 19
// 889.790 us; speedup vs baseline: 1.0197x; 1.0197x over previous
//
#include <hip/hip_runtime.h>

typedef unsigned short ushort_t;
typedef __attribute__((ext_vector_type(4))) float f32x4;
typedef __attribute__((ext_vector_type(8))) short short8;

__device__ __forceinline__ ushort_t f2bf(float f) {
  union { float f; unsigned u; } v; v.f = f;
  unsigned r = v.u + 0x7fffu + ((v.u >> 16) & 1u);
  return (ushort_t)(r >> 16);
}
__device__ __forceinline__ unsigned pack2(float lo, float hi) {
  return (unsigned)f2bf(lo) | ((unsigned)f2bf(hi) << 16);
}

// ---------------- kernel 0a: weights fp32 -> bf16 (wq,wk,wv,wo concatenated) ----
__global__ __launch_bounds__(256) void cvt_w_k(const float* __restrict__ wq,
                                               const float* __restrict__ wk,
                                               const float* __restrict__ wv,
                                               const float* __restrict__ wo,
                                               ushort_t* __restrict__ dst) {
  int idx = (blockIdx.x * 256 + threadIdx.x) * 4;  // 0 .. 1048572
  int m = idx >> 18;
  int off = idx & 0x3ffff;
  const float* s = (m == 0) ? wq : (m == 1) ? wk : (m == 2) ? wv : wo;
  float4 v = *(const float4*)(s + off);
  ushort4 o;
  o.x = f2bf(v.x); o.y = f2bf(v.y); o.z = f2bf(v.z); o.w = f2bf(v.w);
  *(ushort4*)(dst + idx) = o;
}

// ---------------- kernel 0b: x (b,c,192,192) fp32 -> xT[token][c] bf16 ----------
__global__ __launch_bounds__(256) void xpose_k(const float* __restrict__ x,
                                               ushort_t* __restrict__ xT) {
  __shared__ ushort_t tile[128 * 80];  // [c_local][token], padded to 80
  int bid = blockIdx.x;                // 2304 windows * 4 c-chunks
  int win = bid >> 2, kc = bid & 3;
  int b = win / 576, rem = win % 576, wh = rem / 24, ww = rem % 24;
  int tid = threadIdx.x;
  {
    int c_l = tid >> 1, half = tid & 1;
    const float* xb = x + ((((size_t)b * 512 + kc * 128 + c_l) * 192 + wh * 8) * 192 + ww * 8);
#pragma unroll
    for (int ii = 0; ii < 4; ++ii) {
      int i = half * 4 + ii;
      float4 v0 = *(const float4*)(xb + i * 192);
      float4 v1 = *(const float4*)(xb + i * 192 + 4);
      uint4 u;
      u.x = (unsigned)f2bf(v0.x) | ((unsigned)f2bf(v0.y) << 16);
      u.y = (unsigned)f2bf(v0.z) | ((unsigned)f2bf(v0.w) << 16);
      u.z = (unsigned)f2bf(v1.x) | ((unsigned)f2bf(v1.y) << 16);
      u.w = (unsigned)f2bf(v1.z) | ((unsigned)f2bf(v1.w) << 16);
      *(uint4*)&tile[c_l * 80 + i * 8] = u;
    }
  }
  __syncthreads();
  {
    int tok = tid >> 2, q = tid & 3;
    unsigned w[16];
#pragma unroll
    for (int k = 0; k < 16; ++k) {
      unsigned lo = tile[(q * 32 + 2 * k) * 80 + tok];
      unsigned hi = tile[(q * 32 + 2 * k + 1) * 80 + tok];
      w[k] = lo | (hi << 16);
    }
    ushort_t* d = xT + ((size_t)(win * 64 + tok) * 512 + kc * 128 + q * 32);
#pragma unroll
    for (int s2 = 0; s2 < 4; ++s2) {
      uint4 u; u.x = w[s2 * 4 + 0]; u.y = w[s2 * 4 + 1]; u.z = w[s2 * 4 + 2]; u.w = w[s2 * 4 + 3];
      *(uint4*)(d + s2 * 8) = u;
    }
  }
}

// ---------------- kernel 1: fused QKV + attention, 70 KB LDS, 2 blocks/CU -------
// R10/R12-proven body (best measured: ~532-538 us).
__global__ __launch_bounds__(512, 2) void qkv_attn5_k(const ushort_t* __restrict__ xT,
                                                      const ushort_t* __restrict__ wB,
                                                      const float* __restrict__ beta,
                                                      ushort_t* __restrict__ O) {
  // 71680 B total: xstage[2][64][136] | qs[2][64*72] | ks[2][64*72]; vs aliases xstage
  __shared__ __align__(16) ushort_t smem[2 * 8704 + 2 * 4608 + 2 * 4608];
  ushort_t* xstage = smem;            // [2][64][136]
  ushort_t* qs = smem + 17408;        // [2][64*72]  (also reused as P)
  ushort_t* ks = smem + 26624;        // [2][64*72]
  ushort_t* vs = smem;                // [2][64*72]  alias of xstage

  int win = blockIdx.x;
  int t0 = win * 64;
  int tid = threadIdx.x, lane = tid & 63, wid = tid >> 6;  // wid 0..7
  int l15 = lane & 15, l4 = lane >> 4;

  int srow[2], sslot[2];
#pragma unroll
  for (int c = 0; c < 2; ++c) { int u = c * 512 + tid; srow[c] = u >> 4; sslot[c] = u & 15; }

  const f32x4 z = {0.f, 0.f, 0.f, 0.f};

  for (int hcc = 0; hcc < 4; ++hcc) {
    f32x4 aq[4], ak[4], av[4];
#pragma unroll
    for (int i = 0; i < 4; ++i) { aq[i] = z; ak[i] = z; av[i] = z; }
    int ocol = hcc * 128 + wid * 16 + l15;
    const ushort_t* wqr = wB + (size_t)ocol * 512 + l4 * 8;
    const ushort_t* wkr = wqr + 262144;
    const ushort_t* wvr = wqr + 524288;

    // prologue: stage K-chunk 0 into buf 0
#pragma unroll
    for (int c = 0; c < 2; ++c) {
      uint4 v = *(const uint4*)&xT[(size_t)(t0 + srow[c]) * 512 + sslot[c] * 8];
      *(uint4*)&xstage[srow[c] * 136 + sslot[c] * 8] = v;
    }
    __syncthreads();

#pragma unroll
    for (int kb = 0; kb < 4; ++kb) {
      uint4 nx[2];
      if (kb < 3) {  // issue next chunk's loads early; they land after compute
#pragma unroll
        for (int c = 0; c < 2; ++c)
          nx[c] = *(const uint4*)&xT[(size_t)(t0 + srow[c]) * 512 + (kb + 1) * 128 + sslot[c] * 8];
      }
      const ushort_t* xb = xstage + (kb & 1) * 8704;
      __builtin_amdgcn_s_setprio(1);
#pragma unroll
      for (int kkL = 0; kkL < 4; ++kkL) {
        int kk = kb * 4 + kkL;
        short8 bq = *(const short8*)(wqr + kk * 32);
        short8 bk = *(const short8*)(wkr + kk * 32);
        short8 bv = *(const short8*)(wvr + kk * 32);
#pragma unroll
        for (int nt = 0; nt < 4; ++nt) {
          short8 a = *(const short8*)&xb[(nt * 16 + l15) * 136 + kkL * 32 + l4 * 8];
          aq[nt] = __builtin_amdgcn_mfma_f32_16x16x32_bf16(a, bq, aq[nt], 0, 0, 0);
          ak[nt] = __builtin_amdgcn_mfma_f32_16x16x32_bf16(a, bk, ak[nt], 0, 0, 0);
          av[nt] = __builtin_amdgcn_mfma_f32_16x16x32_bf16(a, bv, av[nt], 0, 0, 0);
        }
      }
      __builtin_amdgcn_s_setprio(0);
      if (kb < 3) {
#pragma unroll
        for (int c = 0; c < 2; ++c)
          *(uint4*)&xstage[((kb + 1) & 1) * 8704 + srow[c] * 136 + sslot[c] * 8] = nx[c];
        __syncthreads();
      }
    }
    __syncthreads();  // all QKV xstage reads done (vs aliases xstage region)

    // ---- write q,k (token-major) and v (d-major) to LDS ----
    int hw = wid >> 2;
    int dd = (wid * 16 + l15) & 63;
#pragma unroll
    for (int nt = 0; nt < 4; ++nt) {
#pragma unroll
      for (int r = 0; r < 4; ++r) {
        int n = nt * 16 + l4 * 4 + r;
        qs[hw * 4608 + n * 72 + dd] = f2bf(aq[nt][r]);
        ks[hw * 4608 + n * 72 + dd] = f2bf(ak[nt][r]);
      }
      uint2 u;
      u.x = pack2(av[nt][0], av[nt][1]);
      u.y = pack2(av[nt][2], av[nt][3]);
      *(uint2*)&vs[hw * 4608 + dd * 72 + nt * 16 + l4 * 4] = u;
    }
    __syncthreads();

    // ---- attention: wave -> head hh = wid>>2, rows rowg*16.. ----
    int hh = wid >> 2, rowg = wid & 3;
    int h = hcc * 2 + hh;
    f32x4 sA[4];
#pragma unroll
    for (int i = 0; i < 4; ++i) sA[i] = z;
#pragma unroll
    for (int kk = 0; kk < 2; ++kk) {
      short8 aF = *(const short8*)&qs[hh * 4608 + (rowg * 16 + l15) * 72 + kk * 32 + l4 * 8];
#pragma unroll
      for (int mt = 0; mt < 4; ++mt) {
        short8 bF = *(const short8*)&ks[hh * 4608 + (mt * 16 + l15) * 72 + kk * 32 + l4 * 8];
        sA[mt] = __builtin_amdgcn_mfma_f32_16x16x32_bf16(aF, bF, sA[mt], 0, 0, 0);
      }
    }
    const float* betah = beta + h * 4096;
    float p[4][4];
    float rmax[4] = {-1e30f, -1e30f, -1e30f, -1e30f};
#pragma unroll
    for (int mt = 0; mt < 4; ++mt)
#pragma unroll
      for (int r = 0; r < 4; ++r) {
        int n = rowg * 16 + l4 * 4 + r;
        float val = sA[mt][r] * 0.125f + betah[n * 64 + mt * 16 + l15];
        p[mt][r] = val;
        rmax[r] = fmaxf(rmax[r], val);
      }
#pragma unroll
    for (int m = 1; m <= 8; m <<= 1)
#pragma unroll
      for (int r = 0; r < 4; ++r) rmax[r] = fmaxf(rmax[r], __shfl_xor(rmax[r], m, 64));
    float rsum[4] = {0.f, 0.f, 0.f, 0.f};
#pragma unroll
    for (int mt = 0; mt < 4; ++mt)
#pragma unroll
      for (int r = 0; r < 4; ++r) {
        p[mt][r] = __expf(p[mt][r] - rmax[r]);
        rsum[r] += p[mt][r];
      }
#pragma unroll
    for (int m = 1; m <= 8; m <<= 1)
#pragma unroll
      for (int r = 0; r < 4; ++r) rsum[r] += __shfl_xor(rsum[r], m, 64);
    float rinv[4];
#pragma unroll
    for (int r = 0; r < 4; ++r) rinv[r] = 1.f / rsum[r];
    // P overwrites this wave's own 16 rows of qs[hh]; only reader is this wave's
    // PV (same-wave DS ordering) -> no barrier needed here.
#pragma unroll
    for (int mt = 0; mt < 4; ++mt)
#pragma unroll
      for (int r = 0; r < 4; ++r)
        qs[hh * 4608 + (rowg * 16 + l4 * 4 + r) * 72 + mt * 16 + l15] = f2bf(p[mt][r] * rinv[r]);

    f32x4 oA[4];
#pragma unroll
    for (int i = 0; i < 4; ++i) oA[i] = z;
#pragma unroll
    for (int kk = 0; kk < 2; ++kk) {
      short8 aF = *(const short8*)&qs[hh * 4608 + (rowg * 16 + l15) * 72 + kk * 32 + l4 * 8];
#pragma unroll
      for (int dt = 0; dt < 4; ++dt) {
        short8 bF = *(const short8*)&vs[hh * 4608 + (dt * 16 + l15) * 72 + kk * 32 + l4 * 8];
        oA[dt] = __builtin_amdgcn_mfma_f32_16x16x32_bf16(aF, bF, oA[dt], 0, 0, 0);
      }
    }
#pragma unroll
    for (int dt = 0; dt < 4; ++dt)
#pragma unroll
      for (int r = 0; r < 4; ++r) {
        int n = rowg * 16 + l4 * 4 + r;
        O[(size_t)(t0 + n) * 512 + h * 64 + dt * 16 + l15] = f2bf(oA[dt][r]);
      }
    __syncthreads();  // before next head pair's staging overwrites xstage/vs
  }
}

// ---------------- kernel 2: proj GEMM, 512 thr, one window per block ------------
// Wave w -> o-rows [w*64, +64); O staged ONCE per window (proj_kb staged twice).
// Register-staged issue-early/write-late per kcc chunk.
__global__ __launch_bounds__(512, 2) void proj_kc(const ushort_t* __restrict__ O,
                                                  const ushort_t* __restrict__ woB,
                                                  const float* __restrict__ bo,
                                                  float* __restrict__ out) {
  __shared__ ushort_t ows[64 * 136];
  int bid = blockIdx.x;
  int win = (bid & 7) * 288 + (bid >> 3);  // 2304 = 8*288; neighbors share XCD
  int b = win / 576, rem = win % 576, wh = rem / 24, ww = rem % 24;
  int tid = threadIdx.x, lane = tid & 63, wid = tid >> 6;  // wid 0..7
  int l15 = lane & 15, l4 = lane >> 4;
  int t0 = win * 64;
  const f32x4 z = {0.f, 0.f, 0.f, 0.f};
  f32x4 acc[4][4];
#pragma unroll
  for (int i = 0; i < 4; ++i)
#pragma unroll
    for (int j = 0; j < 4; ++j) acc[i][j] = z;
  // staging: 64 tok x 128 ch = 1024 uint4; 2/thread
  int srow[2], sslot[2];
#pragma unroll
  for (int c = 0; c < 2; ++c) { int u = c * 512 + tid; srow[c] = u >> 4; sslot[c] = u & 15; }
  for (int kcc = 0; kcc < 4; ++kcc) {
    uint4 t[2];
#pragma unroll
    for (int c = 0; c < 2; ++c)
      t[c] = *(const uint4*)&O[(size_t)(t0 + srow[c]) * 512 + kcc * 128 + sslot[c] * 8];
    __syncthreads();  // prev kcc's reads done
#pragma unroll
    for (int c = 0; c < 2; ++c)
      *(uint4*)&ows[srow[c] * 136 + sslot[c] * 8] = t[c];
    __syncthreads();
#pragma unroll
    for (int kk = 0; kk < 4; ++kk) {
      short8 bF[4];
#pragma unroll
      for (int nt = 0; nt < 4; ++nt)
        bF[nt] = *(const short8*)&ows[(nt * 16 + l15) * 136 + kk * 32 + l4 * 8];
      int cg = kcc * 128 + kk * 32 + l4 * 8;
#pragma unroll
      for (int mt = 0; mt < 4; ++mt) {
        int orow = wid * 64 + mt * 16 + l15;
        short8 aF = *(const short8*)(woB + (size_t)orow * 512 + cg);
#pragma unroll
        for (int nt = 0; nt < 4; ++nt)
          acc[mt][nt] = __builtin_amdgcn_mfma_f32_16x16x32_bf16(aF, bF[nt], acc[mt][nt], 0, 0, 0);
      }
    }
  }
#pragma unroll
  for (int mt = 0; mt < 4; ++mt) {
#pragma unroll
    for (int r = 0; r < 4; ++r) {
      int o = wid * 64 + mt * 16 + l4 * 4 + r;
      float bias = bo[o];
#pragma unroll
      for (int nt = 0; nt < 4; ++nt) {
        int tok = nt * 16 + l15;
        int i = tok >> 3, j = tok & 7;
        out[(((size_t)b * 512 + o) * 192 + wh * 8 + i) * 192 + ww * 8 + j] = acc[mt][nt][r] + bias;
      }
    }
  }
}

extern "C" void kernel_launch(void* const* d_in, const int* in_sizes, int n_in,
                              void* d_out, int out_size, void* d_ws, size_t ws_size,
                              hipStream_t stream) {
  const float* x    = (const float*)d_in[0];
  const float* wq   = (const float*)d_in[1];
  const float* wk   = (const float*)d_in[2];
  const float* wv   = (const float*)d_in[3];
  const float* wo   = (const float*)d_in[4];
  const float* bo   = (const float*)d_in[5];
  const float* beta = (const float*)d_in[6];

  // d_ws layout: wB 2 MiB | xT 151 MB | O 151 MB
  ushort_t* wB = (ushort_t*)d_ws;
  ushort_t* xT = (ushort_t*)((char*)d_ws + (size_t)2097152);
  ushort_t* O  = (ushort_t*)((char*)d_ws + (size_t)2097152 + (size_t)147456 * 1024);

  cvt_w_k<<<1024, 256, 0, stream>>>(wq, wk, wv, wo, wB);
  xpose_k<<<2304 * 4, 256, 0, stream>>>(x, xT);
  qkv_attn5_k<<<2304, 512, 0, stream>>>(xT, wB, beta, O);
  proj_kc<<<2304, 512, 0, stream>>>(O, wB + 3 * 262144, bo, (float*)d_out);
}

// Round 20
// 851.608 us; speedup vs baseline: 1.0654x; 1.0448x over previous
//
#include <hip/hip_runtime.h>

typedef unsigned short ushort_t;
typedef __attribute__((ext_vector_type(4))) float f32x4;
typedef __attribute__((ext_vector_type(8))) short short8;

__device__ __forceinline__ ushort_t f2bf(float f) {
  union { float f; unsigned u; } v; v.f = f;
  unsigned r = v.u + 0x7fffu + ((v.u >> 16) & 1u);
  return (ushort_t)(r >> 16);
}
__device__ __forceinline__ unsigned pack2(float lo, float hi) {
  return (unsigned)f2bf(lo) | ((unsigned)f2bf(hi) << 16);
}

// ---------------- kernel 0a: weights fp32 -> bf16 (wq,wk,wv,wo concatenated) ----
__global__ __launch_bounds__(256) void cvt_w_k(const float* __restrict__ wq,
                                               const float* __restrict__ wk,
                                               const float* __restrict__ wv,
                                               const float* __restrict__ wo,
                                               ushort_t* __restrict__ dst) {
  int idx = (blockIdx.x * 256 + threadIdx.x) * 4;  // 0 .. 1048572
  int m = idx >> 18;
  int off = idx & 0x3ffff;
  const float* s = (m == 0) ? wq : (m == 1) ? wk : (m == 2) ? wv : wo;
  float4 v = *(const float4*)(s + off);
  ushort4 o;
  o.x = f2bf(v.x); o.y = f2bf(v.y); o.z = f2bf(v.z); o.w = f2bf(v.w);
  *(ushort4*)(dst + idx) = o;
}

// ---------------- kernel 0b: x (b,c,192,192) fp32 -> xT[token][c] bf16 ----------
__global__ __launch_bounds__(256) void xpose_k(const float* __restrict__ x,
                                               ushort_t* __restrict__ xT) {
  __shared__ ushort_t tile[128 * 80];  // [c_local][token], padded to 80
  int bid = blockIdx.x;                // 2304 windows * 4 c-chunks
  int win = bid >> 2, kc = bid & 3;
  int b = win / 576, rem = win % 576, wh = rem / 24, ww = rem % 24;
  int tid = threadIdx.x;
  {
    int c_l = tid >> 1, half = tid & 1;
    const float* xb = x + ((((size_t)b * 512 + kc * 128 + c_l) * 192 + wh * 8) * 192 + ww * 8);
#pragma unroll
    for (int ii = 0; ii < 4; ++ii) {
      int i = half * 4 + ii;
      float4 v0 = *(const float4*)(xb + i * 192);
      float4 v1 = *(const float4*)(xb + i * 192 + 4);
      uint4 u;
      u.x = (unsigned)f2bf(v0.x) | ((unsigned)f2bf(v0.y) << 16);
      u.y = (unsigned)f2bf(v0.z) | ((unsigned)f2bf(v0.w) << 16);
      u.z = (unsigned)f2bf(v1.x) | ((unsigned)f2bf(v1.y) << 16);
      u.w = (unsigned)f2bf(v1.z) | ((unsigned)f2bf(v1.w) << 16);
      *(uint4*)&tile[c_l * 80 + i * 8] = u;
    }
  }
  __syncthreads();
  {
    int tok = tid >> 2, q = tid & 3;
    unsigned w[16];
#pragma unroll
    for (int k = 0; k < 16; ++k) {
      unsigned lo = tile[(q * 32 + 2 * k) * 80 + tok];
      unsigned hi = tile[(q * 32 + 2 * k + 1) * 80 + tok];
      w[k] = lo | (hi << 16);
    }
    ushort_t* d = xT + ((size_t)(win * 64 + tok) * 512 + kc * 128 + q * 32);
#pragma unroll
    for (int s2 = 0; s2 < 4; ++s2) {
      uint4 u; u.x = w[s2 * 4 + 0]; u.y = w[s2 * 4 + 1]; u.z = w[s2 * 4 + 2]; u.w = w[s2 * 4 + 3];
      *(uint4*)(d + s2 * 8) = u;
    }
  }
}

// ---------------- kernel 1: fused QKV + attention, 70 KB LDS, 2 blocks/CU -------
// R12-proven body (session best: 852.5 us total; this kernel 529-538 us).
__global__ __launch_bounds__(512, 2) void qkv_attn5_k(const ushort_t* __restrict__ xT,
                                                      const ushort_t* __restrict__ wB,
                                                      const float* __restrict__ beta,
                                                      ushort_t* __restrict__ O) {
  // 71680 B total: xstage[2][64][136] | qs[2][64*72] | ks[2][64*72]; vs aliases xstage
  __shared__ __align__(16) ushort_t smem[2 * 8704 + 2 * 4608 + 2 * 4608];
  ushort_t* xstage = smem;            // [2][64][136]
  ushort_t* qs = smem + 17408;        // [2][64*72]  (also reused as P)
  ushort_t* ks = smem + 26624;        // [2][64*72]
  ushort_t* vs = smem;                // [2][64*72]  alias of xstage

  int win = blockIdx.x;
  int t0 = win * 64;
  int tid = threadIdx.x, lane = tid & 63, wid = tid >> 6;  // wid 0..7
  int l15 = lane & 15, l4 = lane >> 4;

  // staging map: two 16B units per thread; u = c*512+tid -> row=u>>4, slot=u&15
  int srow[2], sslot[2];
#pragma unroll
  for (int c = 0; c < 2; ++c) { int u = c * 512 + tid; srow[c] = u >> 4; sslot[c] = u & 15; }

  const f32x4 z = {0.f, 0.f, 0.f, 0.f};

  for (int hcc = 0; hcc < 4; ++hcc) {
    f32x4 aq[4], ak[4], av[4];
#pragma unroll
    for (int i = 0; i < 4; ++i) { aq[i] = z; ak[i] = z; av[i] = z; }
    int ocol = hcc * 128 + wid * 16 + l15;
    const ushort_t* wqr = wB + (size_t)ocol * 512 + l4 * 8;
    const ushort_t* wkr = wqr + 262144;
    const ushort_t* wvr = wqr + 524288;

    // current-weight registers: kk=0 loads issued before the staging barrier
    short8 wqc = *(const short8*)(wqr);
    short8 wkc = *(const short8*)(wkr);
    short8 wvc = *(const short8*)(wvr);

    // prologue: stage K-chunk 0 into buf 0
#pragma unroll
    for (int c = 0; c < 2; ++c) {
      uint4 v = *(const uint4*)&xT[(size_t)(t0 + srow[c]) * 512 + sslot[c] * 8];
      *(uint4*)&xstage[srow[c] * 136 + sslot[c] * 8] = v;
    }
    __syncthreads();

#pragma unroll
    for (int kb = 0; kb < 4; ++kb) {
      uint4 nx[2];
      if (kb < 3) {  // issue next chunk's loads early; they land after compute
#pragma unroll
        for (int c = 0; c < 2; ++c)
          nx[c] = *(const uint4*)&xT[(size_t)(t0 + srow[c]) * 512 + (kb + 1) * 128 + sslot[c] * 8];
      }
      const ushort_t* xb = xstage + (kb & 1) * 8704;
      __builtin_amdgcn_s_setprio(1);
#pragma unroll
      for (int kkL = 0; kkL < 4; ++kkL) {
        int kk = kb * 4 + kkL;
        int kn = (kk + 1) & 15;  // wraps harmlessly at hcc end
        // prefetch kk+1 weights: in flight during this kk's 12 MFMAs
        short8 wqn = *(const short8*)(wqr + kn * 32);
        short8 wkn = *(const short8*)(wkr + kn * 32);
        short8 wvn = *(const short8*)(wvr + kn * 32);
#pragma unroll
        for (int nt = 0; nt < 4; ++nt) {
          short8 a = *(const short8*)&xb[(nt * 16 + l15) * 136 + kkL * 32 + l4 * 8];
          aq[nt] = __builtin_amdgcn_mfma_f32_16x16x32_bf16(a, wqc, aq[nt], 0, 0, 0);
          ak[nt] = __builtin_amdgcn_mfma_f32_16x16x32_bf16(a, wkc, ak[nt], 0, 0, 0);
          av[nt] = __builtin_amdgcn_mfma_f32_16x16x32_bf16(a, wvc, av[nt], 0, 0, 0);
        }
        wqc = wqn; wkc = wkn; wvc = wvn;
      }
      __builtin_amdgcn_s_setprio(0);
      if (kb < 3) {
#pragma unroll
        for (int c = 0; c < 2; ++c)
          *(uint4*)&xstage[((kb + 1) & 1) * 8704 + srow[c] * 136 + sslot[c] * 8] = nx[c];
        __syncthreads();
      }
    }
    __syncthreads();  // all QKV xstage reads done (vs aliases xstage region)

    // ---- write q,k (token-major) and v (d-major) to LDS ----
    int hw = wid >> 2;
    int dd = (wid * 16 + l15) & 63;
#pragma unroll
    for (int nt = 0; nt < 4; ++nt) {
#pragma unroll
      for (int r = 0; r < 4; ++r) {
        int n = nt * 16 + l4 * 4 + r;
        qs[hw * 4608 + n * 72 + dd] = f2bf(aq[nt][r]);
        ks[hw * 4608 + n * 72 + dd] = f2bf(ak[nt][r]);
      }
      uint2 u;
      u.x = pack2(av[nt][0], av[nt][1]);
      u.y = pack2(av[nt][2], av[nt][3]);
      *(uint2*)&vs[hw * 4608 + dd * 72 + nt * 16 + l4 * 4] = u;
    }
    __syncthreads();

    // ---- attention: wave -> head hh = wid>>2, rows rowg*16.. ----
    int hh = wid >> 2, rowg = wid & 3;
    int h = hcc * 2 + hh;
    f32x4 sA[4];
#pragma unroll
    for (int i = 0; i < 4; ++i) sA[i] = z;
#pragma unroll
    for (int kk = 0; kk < 2; ++kk) {
      short8 aF = *(const short8*)&qs[hh * 4608 + (rowg * 16 + l15) * 72 + kk * 32 + l4 * 8];
#pragma unroll
      for (int mt = 0; mt < 4; ++mt) {
        short8 bF = *(const short8*)&ks[hh * 4608 + (mt * 16 + l15) * 72 + kk * 32 + l4 * 8];
        sA[mt] = __builtin_amdgcn_mfma_f32_16x16x32_bf16(aF, bF, sA[mt], 0, 0, 0);
      }
    }
    const float* betah = beta + h * 4096;
    float p[4][4];
    float rmax[4] = {-1e30f, -1e30f, -1e30f, -1e30f};
#pragma unroll
    for (int mt = 0; mt < 4; ++mt)
#pragma unroll
      for (int r = 0; r < 4; ++r) {
        int n = rowg * 16 + l4 * 4 + r;
        float val = sA[mt][r] * 0.125f + betah[n * 64 + mt * 16 + l15];
        p[mt][r] = val;
        rmax[r] = fmaxf(rmax[r], val);
      }
#pragma unroll
    for (int m = 1; m <= 8; m <<= 1)
#pragma unroll
      for (int r = 0; r < 4; ++r) rmax[r] = fmaxf(rmax[r], __shfl_xor(rmax[r], m, 64));
    float rsum[4] = {0.f, 0.f, 0.f, 0.f};
#pragma unroll
    for (int mt = 0; mt < 4; ++mt)
#pragma unroll
      for (int r = 0; r < 4; ++r) {
        p[mt][r] = __expf(p[mt][r] - rmax[r]);
        rsum[r] += p[mt][r];
      }
#pragma unroll
    for (int m = 1; m <= 8; m <<= 1)
#pragma unroll
      for (int r = 0; r < 4; ++r) rsum[r] += __shfl_xor(rsum[r], m, 64);
    float rinv[4];
#pragma unroll
    for (int r = 0; r < 4; ++r) rinv[r] = 1.f / rsum[r];
    // P overwrites this wave's own 16 rows of qs[hh]; only reader is this wave's
    // PV (same-wave DS ordering) -> no barrier needed here.
#pragma unroll
    for (int mt = 0; mt < 4; ++mt)
#pragma unroll
      for (int r = 0; r < 4; ++r)
        qs[hh * 4608 + (rowg * 16 + l4 * 4 + r) * 72 + mt * 16 + l15] = f2bf(p[mt][r] * rinv[r]);

    f32x4 oA[4];
#pragma unroll
    for (int i = 0; i < 4; ++i) oA[i] = z;
#pragma unroll
    for (int kk = 0; kk < 2; ++kk) {
      short8 aF = *(const short8*)&qs[hh * 4608 + (rowg * 16 + l15) * 72 + kk * 32 + l4 * 8];
#pragma unroll
      for (int dt = 0; dt < 4; ++dt) {
        short8 bF = *(const short8*)&vs[hh * 4608 + (dt * 16 + l15) * 72 + kk * 32 + l4 * 8];
        oA[dt] = __builtin_amdgcn_mfma_f32_16x16x32_bf16(aF, bF, oA[dt], 0, 0, 0);
      }
    }
#pragma unroll
    for (int dt = 0; dt < 4; ++dt)
#pragma unroll
      for (int r = 0; r < 4; ++r) {
        int n = rowg * 16 + l4 * 4 + r;
        O[(size_t)(t0 + n) * 512 + h * 64 + dt * 16 + l15] = f2bf(oA[dt][r]);
      }
    __syncthreads();  // before next head pair's staging overwrites xstage/vs
  }
}

// ---------------- kernel 2: proj GEMM (R2 structure + XCD chunk swizzle) --------
__global__ __launch_bounds__(256) void proj_kb(const ushort_t* __restrict__ O,
                                               const ushort_t* __restrict__ woB,
                                               const float* __restrict__ bo,
                                               float* __restrict__ out) {
  __shared__ ushort_t ows[64 * 136];
  int bid = blockIdx.x;
  int wg = (bid & 7) * 576 + (bid >> 3);   // 4608 = 8*576; neighbors share XCD
  int win = wg >> 1, mo = (wg & 1) * 256;
  int b = win / 576, rem = win % 576, wh = rem / 24, ww = rem % 24;
  int tid = threadIdx.x, lane = tid & 63, wid = tid >> 6;
  int l15 = lane & 15, l4 = lane >> 4;
  int t0 = win * 64;
  f32x4 z = {0.f, 0.f, 0.f, 0.f};
  f32x4 acc[4][4];
#pragma unroll
  for (int i = 0; i < 4; ++i)
#pragma unroll
    for (int j = 0; j < 4; ++j) acc[i][j] = z;
  int stok = tid >> 2, sq = tid & 3;
  for (int kcc = 0; kcc < 4; ++kcc) {
    {
      const uint4* src = (const uint4*)(O + ((size_t)(t0 + stok) * 512 + kcc * 128 + sq * 32));
      uint4* dstv = (uint4*)&ows[stok * 136 + sq * 32];
#pragma unroll
      for (int s2 = 0; s2 < 4; ++s2) dstv[s2] = src[s2];
    }
    __syncthreads();
#pragma unroll
    for (int kk = 0; kk < 4; ++kk) {
      short8 bF[4];
#pragma unroll
      for (int nt = 0; nt < 4; ++nt)
        bF[nt] = *(const short8*)&ows[(nt * 16 + l15) * 136 + kk * 32 + l4 * 8];
      int cg = kcc * 128 + kk * 32 + l4 * 8;
#pragma unroll
      for (int mt = 0; mt < 4; ++mt) {
        int orow = mo + wid * 64 + mt * 16 + l15;
        short8 aF = *(const short8*)(woB + (size_t)orow * 512 + cg);
#pragma unroll
        for (int nt = 0; nt < 4; ++nt)
          acc[mt][nt] = __builtin_amdgcn_mfma_f32_16x16x32_bf16(aF, bF[nt], acc[mt][nt], 0, 0, 0);
      }
    }
    __syncthreads();
  }
#pragma unroll
  for (int mt = 0; mt < 4; ++mt) {
#pragma unroll
    for (int r = 0; r < 4; ++r) {
      int o = mo + wid * 64 + mt * 16 + l4 * 4 + r;
      float bias = bo[o];
#pragma unroll
      for (int nt = 0; nt < 4; ++nt) {
        int tok = nt * 16 + l15;
        int i = tok >> 3, j = tok & 7;
        out[(((size_t)b * 512 + o) * 192 + wh * 8 + i) * 192 + ww * 8 + j] = acc[mt][nt][r] + bias;
      }
    }
  }
}

extern "C" void kernel_launch(void* const* d_in, const int* in_sizes, int n_in,
                              void* d_out, int out_size, void* d_ws, size_t ws_size,
                              hipStream_t stream) {
  const float* x    = (const float*)d_in[0];
  const float* wq   = (const float*)d_in[1];
  const float* wk   = (const float*)d_in[2];
  const float* wv   = (const float*)d_in[3];
  const float* wo   = (const float*)d_in[4];
  const float* bo   = (const float*)d_in[5];
  const float* beta = (const float*)d_in[6];

  // d_ws layout: wB 2 MiB | xT 151 MB | O 151 MB
  ushort_t* wB = (ushort_t*)d_ws;
  ushort_t* xT = (ushort_t*)((char*)d_ws + (size_t)2097152);
  ushort_t* O  = (ushort_t*)((char*)d_ws + (size_t)2097152 + (size_t)147456 * 1024);

  cvt_w_k<<<1024, 256, 0, stream>>>(wq, wk, wv, wo, wB);
  xpose_k<<<2304 * 4, 256, 0, stream>>>(x, xT);
  qkv_attn5_k<<<2304, 512, 0, stream>>>(xT, wB, beta, O);
  proj_kb<<<4608, 256, 0, stream>>>(O, wB + 3 * 262144, bo, (float*)d_out);
}